// Round 1
// baseline (69537.939 us; speedup 1.0000x reference)
//
#include <hip/hip_runtime.h>
#include <cmath>

#define Tn 512
#define Bn 32
#define Hn 1024
#define G4n 4096

// ---------------------------------------------------------------------------
// init: zero h0 (32x1024) and c_state (32x1024); ws is poisoned 0xAA each call
// ---------------------------------------------------------------------------
__global__ void lstm_init_f32(float4* __restrict__ h0, float4* __restrict__ cs) {
    int i = blockIdx.x * blockDim.x + threadIdx.x;   // 0..16383
    float4 z = make_float4(0.f, 0.f, 0.f, 0.f);
    if (i < 8192) h0[i] = z;
    else          cs[i - 8192] = z;
}

// ---------------------------------------------------------------------------
// Phase 1: xg[m][n] = sum_k x[b][t][k] * w_ih[n][k] + b_ih[n] + b_hh[n]
//   m = t*32 + b  (M=16384), n in [0,4096), K=1024, all fp32.
//   128x128 tile, BK=16, 256 threads, 8x8 micro-tile.
// ---------------------------------------------------------------------------
__global__ __launch_bounds__(256) void xg_gemm_f32(
    const float* __restrict__ x, const float* __restrict__ w_ih,
    const float* __restrict__ b_ih, const float* __restrict__ b_hh,
    float* __restrict__ xg)
{
    __shared__ float As[16][132];   // [k][m], padded
    __shared__ float Bs[16][132];   // [k][n], padded

    const int tid = threadIdx.x;
    const int m0 = blockIdx.x * 128;
    const int n0 = blockIdx.y * 128;
    const int tx = tid & 15;        // n-dir
    const int ty = tid >> 4;        // m-dir

    // staging: thread loads 2 float4 of A and 2 of B per k-tile
    const int lrow = tid >> 1;              // 0..127
    const int lk   = (tid & 1) * 8;         // 0 or 8
    const int am   = m0 + lrow;             // m index -> (b = am&31, t = am>>5)
    const float* aptr = x + ((size_t)(am & 31) * Tn + (size_t)(am >> 5)) * Hn + lk;
    const float* bptr = w_ih + (size_t)(n0 + lrow) * Hn + lk;

    float acc[8][8];
    #pragma unroll
    for (int i = 0; i < 8; ++i)
        #pragma unroll
        for (int j = 0; j < 8; ++j) acc[i][j] = 0.f;

    for (int kt = 0; kt < Hn; kt += 16) {
        float4 av0 = *(const float4*)(aptr + kt);
        float4 av1 = *(const float4*)(aptr + kt + 4);
        float4 bv0 = *(const float4*)(bptr + kt);
        float4 bv1 = *(const float4*)(bptr + kt + 4);
        __syncthreads();   // previous tile fully consumed
        As[lk + 0][lrow] = av0.x; As[lk + 1][lrow] = av0.y;
        As[lk + 2][lrow] = av0.z; As[lk + 3][lrow] = av0.w;
        As[lk + 4][lrow] = av1.x; As[lk + 5][lrow] = av1.y;
        As[lk + 6][lrow] = av1.z; As[lk + 7][lrow] = av1.w;
        Bs[lk + 0][lrow] = bv0.x; Bs[lk + 1][lrow] = bv0.y;
        Bs[lk + 2][lrow] = bv0.z; Bs[lk + 3][lrow] = bv0.w;
        Bs[lk + 4][lrow] = bv1.x; Bs[lk + 5][lrow] = bv1.y;
        Bs[lk + 6][lrow] = bv1.z; Bs[lk + 7][lrow] = bv1.w;
        __syncthreads();
        #pragma unroll
        for (int kk = 0; kk < 16; ++kk) {
            float a[8], b[8];
            *(float4*)&a[0] = *(const float4*)&As[kk][ty * 4];
            *(float4*)&a[4] = *(const float4*)&As[kk][64 + ty * 4];
            *(float4*)&b[0] = *(const float4*)&Bs[kk][tx * 4];
            *(float4*)&b[4] = *(const float4*)&Bs[kk][64 + tx * 4];
            #pragma unroll
            for (int i = 0; i < 8; ++i)
                #pragma unroll
                for (int j = 0; j < 8; ++j)
                    acc[i][j] = fmaf(a[i], b[j], acc[i][j]);
        }
    }

    // epilogue: + (b_ih + b_hh), store
    float bias[8];
    {
        float4 bi0 = *(const float4*)(b_ih + n0 + tx * 4);
        float4 bh0 = *(const float4*)(b_hh + n0 + tx * 4);
        float4 bi1 = *(const float4*)(b_ih + n0 + 64 + tx * 4);
        float4 bh1 = *(const float4*)(b_hh + n0 + 64 + tx * 4);
        bias[0] = bi0.x + bh0.x; bias[1] = bi0.y + bh0.y;
        bias[2] = bi0.z + bh0.z; bias[3] = bi0.w + bh0.w;
        bias[4] = bi1.x + bh1.x; bias[5] = bi1.y + bh1.y;
        bias[6] = bi1.z + bh1.z; bias[7] = bi1.w + bh1.w;
    }
    #pragma unroll
    for (int i = 0; i < 8; ++i) {
        int mrow = m0 + ((i < 4) ? (ty * 4 + i) : (64 + ty * 4 + (i - 4)));
        float* orow = xg + (size_t)mrow * G4n + n0;
        float4 s0 = make_float4(acc[i][0] + bias[0], acc[i][1] + bias[1],
                                acc[i][2] + bias[2], acc[i][3] + bias[3]);
        float4 s1 = make_float4(acc[i][4] + bias[4], acc[i][5] + bias[5],
                                acc[i][6] + bias[6], acc[i][7] + bias[7]);
        *(float4*)(orow + tx * 4)      = s0;
        *(float4*)(orow + 64 + tx * 4) = s1;
    }
}

// ---------------------------------------------------------------------------
// Phase 2 step: gates = xg_t + h_in @ w_hh^T ; LSTM cell update.
//   grid 256 blocks x 256 thr. Block bj owns h-columns [4*bj, 4*bj+4) for all
//   32 batches x 4 gates. tid = ks*128 + b*4 + cl (ks = k-half).
//   h staged in exactly 64 KB LDS (two 512-k passes), XOR-swizzled float4
//   chunks -> 2-way banks (free). LDS reused as reduction scratch after.
//   PRE=1: xg precomputed in ws. PRE=0: fallback recomputes x-projection.
// ---------------------------------------------------------------------------
template<int PRE>
__global__ __launch_bounds__(256) void lstm_step_f32(
    const float* __restrict__ xg_t,
    const float* __restrict__ x,
    const float* __restrict__ w_ih,
    const float* __restrict__ bi,
    const float* __restrict__ bh,
    const float* __restrict__ w_hh,
    int t,
    const float* __restrict__ h_in,
    float* __restrict__ h_out,
    float* __restrict__ c_state,
    float* __restrict__ out,
    int write_out)
{
    __shared__ float4 h4[32 * 128];    // 64 KB: [b][chunk^b], chunk = k/4 within pass

    const int tid = threadIdx.x;
    const int ks = tid >> 7;           // k-half 0/1
    const int r  = tid & 127;
    const int b  = r >> 2;             // 0..31
    const int cl = r & 3;
    const int c  = blockIdx.x * 4 + cl;

    const float* wp0 = w_hh + (size_t)(0 * Hn + c) * Hn;
    const float* wp1 = w_hh + (size_t)(1 * Hn + c) * Hn;
    const float* wp2 = w_hh + (size_t)(2 * Hn + c) * Hn;
    const float* wp3 = w_hh + (size_t)(3 * Hn + c) * Hn;
    const float* xb = nullptr;
    const float *wi0 = nullptr, *wi1 = nullptr, *wi2 = nullptr, *wi3 = nullptr;
    if (!PRE) {
        xb  = x + ((size_t)b * Tn + (size_t)t) * Hn;
        wi0 = w_ih + (size_t)(0 * Hn + c) * Hn;
        wi1 = w_ih + (size_t)(1 * Hn + c) * Hn;
        wi2 = w_ih + (size_t)(2 * Hn + c) * Hn;
        wi3 = w_ih + (size_t)(3 * Hn + c) * Hn;
    }

    float a0 = 0.f, a1 = 0.f, a2 = 0.f, a3 = 0.f;

    for (int p = 0; p < 2; ++p) {
        __syncthreads();               // previous pass fully consumed
        #pragma unroll 4
        for (int i = 0; i < 16; ++i) { // stage 64 KB: 4096 float4 / 256 thr
            int f  = i * 256 + tid;    // 0..4095
            int bb = f >> 7;           // batch row
            int g4 = f & 127;          // chunk within pass
            float4 v = *(const float4*)(h_in + (size_t)bb * Hn + p * 512 + g4 * 4);
            h4[bb * 128 + (g4 ^ bb)] = v;
        }
        __syncthreads();
        const int ko = p * 512 + ks * 256;   // this thread's k-offset
        const int cb = ks * 64;              // chunk base within pass
        #pragma unroll 4
        for (int kk = 0; kk < 64; ++kk) {
            float4 hv = h4[b * 128 + ((cb + kk) ^ b)];
            float4 w0 = *(const float4*)(wp0 + ko + kk * 4);
            float4 w1 = *(const float4*)(wp1 + ko + kk * 4);
            float4 w2 = *(const float4*)(wp2 + ko + kk * 4);
            float4 w3 = *(const float4*)(wp3 + ko + kk * 4);
            a0 += hv.x * w0.x + hv.y * w0.y + hv.z * w0.z + hv.w * w0.w;
            a1 += hv.x * w1.x + hv.y * w1.y + hv.z * w1.z + hv.w * w1.w;
            a2 += hv.x * w2.x + hv.y * w2.y + hv.z * w2.z + hv.w * w2.w;
            a3 += hv.x * w3.x + hv.y * w3.y + hv.z * w3.z + hv.w * w3.w;
            if (!PRE) {
                float4 xv = *(const float4*)(xb + ko + kk * 4);
                float4 u0 = *(const float4*)(wi0 + ko + kk * 4);
                float4 u1 = *(const float4*)(wi1 + ko + kk * 4);
                float4 u2 = *(const float4*)(wi2 + ko + kk * 4);
                float4 u3 = *(const float4*)(wi3 + ko + kk * 4);
                a0 += xv.x * u0.x + xv.y * u0.y + xv.z * u0.z + xv.w * u0.w;
                a1 += xv.x * u1.x + xv.y * u1.y + xv.z * u1.z + xv.w * u1.w;
                a2 += xv.x * u2.x + xv.y * u2.y + xv.z * u2.z + xv.w * u2.w;
                a3 += xv.x * u3.x + xv.y * u3.y + xv.z * u3.z + xv.w * u3.w;
            }
        }
    }

    // combine k-halves + cell update (LDS reused as scratch)
    __syncthreads();
    float* red = (float*)h4;           // 256*4 floats = 4 KB
    red[tid * 4 + 0] = a0; red[tid * 4 + 1] = a1;
    red[tid * 4 + 2] = a2; red[tid * 4 + 3] = a3;
    __syncthreads();
    if (tid < 128) {
        const int bb = tid >> 2;
        const int cc = blockIdx.x * 4 + (tid & 3);
        float gi = red[tid * 4 + 0] + red[(tid + 128) * 4 + 0];
        float gf = red[tid * 4 + 1] + red[(tid + 128) * 4 + 1];
        float gg = red[tid * 4 + 2] + red[(tid + 128) * 4 + 2];
        float go = red[tid * 4 + 3] + red[(tid + 128) * 4 + 3];
        if (PRE) {
            gi += xg_t[(size_t)bb * G4n + 0 * Hn + cc];
            gf += xg_t[(size_t)bb * G4n + 1 * Hn + cc];
            gg += xg_t[(size_t)bb * G4n + 2 * Hn + cc];
            go += xg_t[(size_t)bb * G4n + 3 * Hn + cc];
        } else {
            gi += bi[0 * Hn + cc] + bh[0 * Hn + cc];
            gf += bi[1 * Hn + cc] + bh[1 * Hn + cc];
            gg += bi[2 * Hn + cc] + bh[2 * Hn + cc];
            go += bi[3 * Hn + cc] + bh[3 * Hn + cc];
        }
        float iv = 1.f / (1.f + expf(-gi));
        float fv = 1.f / (1.f + expf(-gf));
        float gv = tanhf(gg);
        float ov = 1.f / (1.f + expf(-go));
        int idx = bb * Hn + cc;
        float cn = fv * c_state[idx] + iv * gv;
        float hn = ov * tanhf(cn);
        c_state[idx] = cn;
        h_out[idx] = hn;
        if (write_out) out[idx] = hn;
    }
}

// ---------------------------------------------------------------------------
extern "C" void kernel_launch(void* const* d_in, const int* in_sizes, int n_in,
                              void* d_out, int out_size, void* d_ws, size_t ws_size,
                              hipStream_t stream) {
    const float* x    = (const float*)d_in[0];
    const float* w_ih = (const float*)d_in[1];
    const float* w_hh = (const float*)d_in[2];
    const float* b_ih = (const float*)d_in[3];
    const float* b_hh = (const float*)d_in[4];
    float* out = (float*)d_out;

    char* ws = (char*)d_ws;
    float* h0 = (float*)(ws);
    float* h1 = (float*)(ws + (128 << 10));
    float* cs = (float*)(ws + (256 << 10));
    float* xg = (float*)(ws + (384 << 10));

    const size_t need = (size_t)(384 << 10) + (size_t)Tn * Bn * G4n * sizeof(float);
    const bool pre = ws_size >= need;   // constant across calls -> graph-safe

    lstm_init_f32<<<dim3(64), dim3(256), 0, stream>>>((float4*)h0, (float4*)cs);

    if (pre) {
        xg_gemm_f32<<<dim3(128, 32), dim3(256), 0, stream>>>(x, w_ih, b_ih, b_hh, xg);
        for (int t = 0; t < Tn; ++t) {
            const float* hin = (t & 1) ? h1 : h0;
            float* hout      = (t & 1) ? h0 : h1;
            lstm_step_f32<1><<<dim3(256), dim3(256), 0, stream>>>(
                xg + (size_t)t * Bn * G4n, nullptr, nullptr, nullptr, nullptr,
                w_hh, t, hin, hout, cs, out, (t == Tn - 1) ? 1 : 0);
        }
    } else {
        for (int t = 0; t < Tn; ++t) {
            const float* hin = (t & 1) ? h1 : h0;
            float* hout      = (t & 1) ? h0 : h1;
            lstm_step_f32<0><<<dim3(256), dim3(256), 0, stream>>>(
                nullptr, x, w_ih, b_ih, b_hh,
                w_hh, t, hin, hout, cs, out, (t == Tn - 1) ? 1 : 0);
        }
    }
}

// Round 2
// 65808.197 us; speedup vs baseline: 1.0567x; 1.0567x over previous
//
#include <hip/hip_runtime.h>
#include <cmath>

#define Tn 512
#define Bn 32
#define Hn 1024
#define G4n 4096

// ---------------------------------------------------------------------------
// init: zero h0 (32x1024) and c_state (32x1024); ws is poisoned 0xAA each call
// ---------------------------------------------------------------------------
__global__ void lstm_init_f32(float4* __restrict__ h0, float4* __restrict__ cs) {
    int i = blockIdx.x * blockDim.x + threadIdx.x;   // 0..16383
    float4 z = make_float4(0.f, 0.f, 0.f, 0.f);
    if (i < 8192) h0[i] = z;
    else          cs[i - 8192] = z;
}

// ---------------------------------------------------------------------------
// Fused LSTM step: gates[b][n] = x[b,t,:]·w_ih[n,:] + h[b,:]·w_hh[n,:] + bias
// then cell update. No precomputed xg, no big LDS.
//
// grid 256 blocks x 1024 threads (16 waves/CU, 4/SIMD).
// Block bj owns columns c = 4*bj..4*bj+3, all 4 gates, all 32 batches.
// Thread tid = q*128 + r*8 + bg:
//   q  in [0,8): k-eighth. q<4 -> x-part (k = (q&3)*256..), q>=4 -> h-part.
//   r  in [0,16): row-in-block; gate g = r&3, col cl = r>>2;
//                 n = g*1024 + bj*4 + cl.
//   bg in [0,8): batch group, b = bg*4 + {0..3} -> 4 accumulators/thread.
// Inner iter (64x): 1 w float4 (8-way lane broadcast) + 4 a float4 (8-way
// lane broadcast, 16-way cross-wave L1 reuse) + 16 FMA  -> VALU-bound.
// Reduction: 16 KB LDS, 8 q-partials summed per (b, col), then activations.
// ---------------------------------------------------------------------------
__global__ __launch_bounds__(1024) void lstm_step_fused(
    const float* __restrict__ x,      // [B,T,H]
    const float* __restrict__ w_ih,   // [4H,H]
    const float* __restrict__ w_hh,   // [4H,H]
    const float* __restrict__ b_ih,   // [4H]
    const float* __restrict__ b_hh,   // [4H]
    int t,
    const float* __restrict__ h_in,   // [B,H]
    float* __restrict__ h_out,        // [B,H]
    float* __restrict__ c_state,      // [B,H]
    float* __restrict__ out,          // [B,H]
    int write_out)
{
    __shared__ float4 part[1024];     // 16 KB

    const int tid = threadIdx.x;
    const int q   = tid >> 7;         // 0..7 (wave-uniform)
    const int r   = (tid >> 3) & 15;  // 0..15
    const int bg  = tid & 7;          // 0..7
    const int bj  = blockIdx.x;       // 0..255
    const int g   = r & 3;
    const int cl  = r >> 2;
    const int n   = g * Hn + bj * 4 + cl;

    const int kq = (q & 3) * 256;     // k-offset within the 1024-k matrix
    const float* w = ((q < 4) ? w_ih : w_hh) + (size_t)n * Hn + kq;

    const float* abase;
    size_t astride;
    if (q < 4) { abase = x + (size_t)t * Hn + kq; astride = (size_t)Tn * Hn; }
    else       { abase = h_in + kq;               astride = (size_t)Hn; }
    const float* a0 = abase + (size_t)(bg * 4 + 0) * astride;
    const float* a1 = abase + (size_t)(bg * 4 + 1) * astride;
    const float* a2 = abase + (size_t)(bg * 4 + 2) * astride;
    const float* a3 = abase + (size_t)(bg * 4 + 3) * astride;

    float c0 = 0.f, c1 = 0.f, c2 = 0.f, c3 = 0.f;
    #pragma unroll 2
    for (int kk = 0; kk < 64; ++kk) {
        float4 wv = *(const float4*)(w  + kk * 4);
        float4 v0 = *(const float4*)(a0 + kk * 4);
        float4 v1 = *(const float4*)(a1 + kk * 4);
        float4 v2 = *(const float4*)(a2 + kk * 4);
        float4 v3 = *(const float4*)(a3 + kk * 4);
        c0 += wv.x * v0.x + wv.y * v0.y + wv.z * v0.z + wv.w * v0.w;
        c1 += wv.x * v1.x + wv.y * v1.y + wv.z * v1.z + wv.w * v1.w;
        c2 += wv.x * v2.x + wv.y * v2.y + wv.z * v2.z + wv.w * v2.w;
        c3 += wv.x * v3.x + wv.y * v3.y + wv.z * v3.z + wv.w * v3.w;
    }
    part[tid] = make_float4(c0, c1, c2, c3);
    __syncthreads();

    // finalize: 128 threads, one per (b, cl)
    if (tid < 128) {
        const int b   = tid >> 2;
        const int cl2 = tid & 3;
        const int col = bj * 4 + cl2;
        float gate[4];
        #pragma unroll
        for (int g2 = 0; g2 < 4; ++g2) {
            const int n2 = g2 * Hn + col;
            const int rr = cl2 * 4 + g2;          // r with r&3==g2, r>>2==cl2
            float s = b_ih[n2] + b_hh[n2];
            #pragma unroll
            for (int qq = 0; qq < 8; ++qq) {
                const float* p = (const float*)&part[qq * 128 + rr * 8 + (b >> 2)];
                s += p[b & 3];
            }
            gate[g2] = s;
        }
        const float iv = 1.f / (1.f + expf(-gate[0]));
        const float fv = 1.f / (1.f + expf(-gate[1]));
        const float gv = tanhf(gate[2]);
        const float ov = 1.f / (1.f + expf(-gate[3]));
        const int idx = b * Hn + col;
        const float cn = fv * c_state[idx] + iv * gv;
        const float hn = ov * tanhf(cn);
        c_state[idx] = cn;
        h_out[idx] = hn;
        if (write_out) out[idx] = hn;
    }
}

// ---------------------------------------------------------------------------
extern "C" void kernel_launch(void* const* d_in, const int* in_sizes, int n_in,
                              void* d_out, int out_size, void* d_ws, size_t ws_size,
                              hipStream_t stream) {
    const float* x    = (const float*)d_in[0];
    const float* w_ih = (const float*)d_in[1];
    const float* w_hh = (const float*)d_in[2];
    const float* b_ih = (const float*)d_in[3];
    const float* b_hh = (const float*)d_in[4];
    float* out = (float*)d_out;

    char* ws = (char*)d_ws;
    float* h0 = (float*)(ws);                  // 128 KB
    float* h1 = (float*)(ws + (128 << 10));    // 128 KB
    float* cs = (float*)(ws + (256 << 10));    // 128 KB
    (void)ws_size; (void)in_sizes; (void)n_in; (void)out_size;

    lstm_init_f32<<<dim3(64), dim3(256), 0, stream>>>((float4*)h0, (float4*)cs);

    for (int t = 0; t < Tn; ++t) {
        const float* hin = (t & 1) ? h1 : h0;
        float* hout      = (t & 1) ? h0 : h1;
        lstm_step_fused<<<dim3(256), dim3(1024), 0, stream>>>(
            x, w_ih, w_hh, b_ih, b_hh, t, hin, hout, cs, out,
            (t == Tn - 1) ? 1 : 0);
    }
}

// Round 4
// 7366.574 us; speedup vs baseline: 9.4397x; 8.9334x over previous
//
#include <hip/hip_runtime.h>
#include <cmath>

#define Tn 512
#define Bn 32
#define Hn 1024

typedef short bf16x8 __attribute__((ext_vector_type(8)));
typedef float f32x4 __attribute__((ext_vector_type(4)));

__device__ __forceinline__ unsigned short f2bf_rne(float f) {
    unsigned u = __float_as_uint(f);
    unsigned r = (u + 0x7fffu + ((u >> 16) & 1u)) >> 16;
    return (unsigned short)r;
}
__device__ __forceinline__ float bf2f(unsigned short h) {
    return __uint_as_float((unsigned)h << 16);
}
__device__ __forceinline__ bf16x8 cvt8(float4 a, float4 b) {
    union { unsigned u[4]; bf16x8 v; } o;
    o.u[0] = (unsigned)f2bf_rne(a.x) | ((unsigned)f2bf_rne(a.y) << 16);
    o.u[1] = (unsigned)f2bf_rne(a.z) | ((unsigned)f2bf_rne(a.w) << 16);
    o.u[2] = (unsigned)f2bf_rne(b.x) | ((unsigned)f2bf_rne(b.y) << 16);
    o.u[3] = (unsigned)f2bf_rne(b.z) | ((unsigned)f2bf_rne(b.w) << 16);
    return o.v;
}
__device__ __forceinline__ bf16x8 as_bf8(uint4 u) {
    union { uint4 q; bf16x8 v; } o; o.q = u; return o.v;
}

// flags zeroed every call (ws is re-poisoned 0xAA before each timed launch)
__global__ void lstm_flags_init(unsigned* flags) { flags[threadIdx.x] = 0u; }

// ---------------------------------------------------------------------------
// Persistent bf16-MFMA LSTM. 256 blocks (1/CU via 146.5 KB LDS) x 512 thr.
// Block bj owns n-rows r=0..15 (gate=r>>2, col=bj*4+(r&3)) x 32 batches.
//   - W staged once to LDS as SPLIT bf16: rows 0..15 = hi, 16..31 = lo
//     (lo = rne(w - hi)); stride 2056 bf16 pads ds_read_b128 bank-balanced.
//   - per step: G[16x32] = (Whi+Wlo)[16x2048] . a^T, a = concat(x_t, h(t-1)).
//     Wave wv = k-slice of 256 (128 x-k + 128 h-k), both 16-batch tiles.
//     B-frags per-lane DIRECT from global: x fp32 + in-reg RNE cvt; h bf16.
//     MFMA layouts (HW-verified): A[m=l&15][k=q*8+j], B[k=q*8+j][n=l&15],
//     D col=l&15,row=q*4+reg.
//   - x-phase before the grid-barrier poll (no dependency) hides latency.
//   - 8-way k-reduce via 16 KB LDS; c-state in registers; h bf16 in ws
//     double buffer; barrier = 256-flag array + agent release/acquire fences.
// ---------------------------------------------------------------------------
__global__ __launch_bounds__(512, 2) void lstm_persist_mfma(
    const float* __restrict__ x,       // [B,T,H] fp32
    const float* __restrict__ w_ih,    // [4H,H] fp32
    const float* __restrict__ w_hh,    // [4H,H] fp32
    const float* __restrict__ b_ih,    // [4H]
    const float* __restrict__ b_hh,    // [4H]
    unsigned short* __restrict__ hbuf, // ws: 2 x [32][1024] bf16
    unsigned* __restrict__ flags,      // ws: [256] u32, zeroed
    float* __restrict__ out)           // [B,H] fp32
{
    extern __shared__ char smem[];
    unsigned short* lds_w = (unsigned short*)smem;            // 32 x 2056 bf16 = 131584 B
    float* lds_r = (float*)(smem + 131584);                   // 16 tiles x 256 f32 = 16 KB
    float* lds_g = (float*)(smem + 131584 + 16384);           // 16 x 32 f32 = 2 KB

    const int tid = threadIdx.x;
    const int bj  = blockIdx.x;
    const int wv  = tid >> 6;          // 0..7  k-slice
    const int ln  = tid & 63;
    const int l15 = ln & 15;
    const int qd  = ln >> 4;           // 0..3

    // ---- stage W (hi+lo) into LDS, once ----
    for (int i = 0; i < 16; ++i) {
        int slot = i * 512 + tid;      // 8192 float4 slots = 16 rows x 512
        int r    = slot >> 9;
        int f4   = slot & 511;
        int n    = (r >> 2) * Hn + bj * 4 + (r & 3);
        float4 v = (f4 < 256) ? ((const float4*)(w_ih + (size_t)n * Hn))[f4]
                              : ((const float4*)(w_hh + (size_t)n * Hn))[f4 - 256];
        unsigned short h0 = f2bf_rne(v.x), h1 = f2bf_rne(v.y);
        unsigned short h2 = f2bf_rne(v.z), h3 = f2bf_rne(v.w);
        unsigned short l0 = f2bf_rne(v.x - bf2f(h0)), l1 = f2bf_rne(v.y - bf2f(h1));
        unsigned short l2 = f2bf_rne(v.z - bf2f(h2)), l3 = f2bf_rne(v.w - bf2f(h3));
        uint2 ph, pl;
        ph.x = (unsigned)h0 | ((unsigned)h1 << 16);
        ph.y = (unsigned)h2 | ((unsigned)h3 << 16);
        pl.x = (unsigned)l0 | ((unsigned)l1 << 16);
        pl.y = (unsigned)l2 | ((unsigned)l3 << 16);
        *(uint2*)(lds_w + (size_t)r        * 2056 + f4 * 4) = ph;
        *(uint2*)(lds_w + (size_t)(r + 16) * 2056 + f4 * 4) = pl;
    }

    // ---- finalize-thread state: bias regs + register c-state ----
    float bias0 = 0.f, bias1 = 0.f, bias2 = 0.f, bias3 = 0.f, creg = 0.f;
    if (tid < 128) {
        int col = bj * 4 + (tid & 3);
        bias0 = b_ih[col]          + b_hh[col];
        bias1 = b_ih[Hn + col]     + b_hh[Hn + col];
        bias2 = b_ih[2 * Hn + col] + b_hh[2 * Hn + col];
        bias3 = b_ih[3 * Hn + col] + b_hh[3 * Hn + col];
    }
    __syncthreads();

    // per-lane bases
    const unsigned short* whi_base = lds_w + (size_t)l15 * 2056 + qd * 8;
    const unsigned short* wlo_base = lds_w + (size_t)(l15 + 16) * 2056 + qd * 8;
    const float* xr0 = x + (size_t)l15        * (Tn * Hn) + wv * 128 + qd * 8;
    const float* xr1 = x + (size_t)(16 + l15) * (Tn * Hn) + wv * 128 + qd * 8;
    const size_t hoff0 = (size_t)l15        * Hn + wv * 128 + qd * 8;
    const size_t hoff1 = (size_t)(16 + l15) * Hn + wv * 128 + qd * 8;

    for (int t = 0; t < Tn; ++t) {
        f32x4 acc0 = {0.f, 0.f, 0.f, 0.f};   // batches  0..15
        f32x4 acc1 = {0.f, 0.f, 0.f, 0.f};   // batches 16..31

        // ---- x-phase (no dependency on other blocks) ----
        {
            const float* p0 = xr0 + (size_t)t * Hn;
            const float* p1 = xr1 + (size_t)t * Hn;
            float4 xa0[4], xb0[4], xa1[4], xb1[4];
            #pragma unroll
            for (int j = 0; j < 4; ++j) {
                xa0[j] = *(const float4*)(p0 + j * 32);
                xb0[j] = *(const float4*)(p0 + j * 32 + 4);
                xa1[j] = *(const float4*)(p1 + j * 32);
                xb1[j] = *(const float4*)(p1 + j * 32 + 4);
            }
            #pragma unroll
            for (int j = 0; j < 4; ++j) {
                const int koff = wv * 128 + j * 32;
                bf16x8 ahi = *(const bf16x8*)(whi_base + koff);
                bf16x8 alo = *(const bf16x8*)(wlo_base + koff);
                bf16x8 bf0 = cvt8(xa0[j], xb0[j]);
                bf16x8 bf1 = cvt8(xa1[j], xb1[j]);
                acc0 = __builtin_amdgcn_mfma_f32_16x16x32_bf16(ahi, bf0, acc0, 0, 0, 0);
                acc0 = __builtin_amdgcn_mfma_f32_16x16x32_bf16(alo, bf0, acc0, 0, 0, 0);
                acc1 = __builtin_amdgcn_mfma_f32_16x16x32_bf16(ahi, bf1, acc1, 0, 0, 0);
                acc1 = __builtin_amdgcn_mfma_f32_16x16x32_bf16(alo, bf1, acc1, 0, 0, 0);
            }
        }

        // ---- grid barrier: all blocks finished step t-1 ----
        if (t > 0) {
            if (wv == 0) {
                const unsigned* fp = flags + ln * 4;
                for (;;) {
                    unsigned m0 = __hip_atomic_load(fp + 0, __ATOMIC_RELAXED, __HIP_MEMORY_SCOPE_AGENT);
                    unsigned m1 = __hip_atomic_load(fp + 1, __ATOMIC_RELAXED, __HIP_MEMORY_SCOPE_AGENT);
                    unsigned m2 = __hip_atomic_load(fp + 2, __ATOMIC_RELAXED, __HIP_MEMORY_SCOPE_AGENT);
                    unsigned m3 = __hip_atomic_load(fp + 3, __ATOMIC_RELAXED, __HIP_MEMORY_SCOPE_AGENT);
                    unsigned mn = m0 < m1 ? m0 : m1;
                    unsigned mo = m2 < m3 ? m2 : m3;
                    mn = mn < mo ? mn : mo;
                    if (__all((int)(mn >= (unsigned)t))) break;
                    __builtin_amdgcn_s_sleep(8);
                }
                __builtin_amdgcn_fence(__ATOMIC_ACQUIRE, "agent");
            }
            __syncthreads();

            // ---- h-phase: h(t-1) bf16 from ws ----
            const unsigned short* hb = hbuf + (size_t)((t - 1) & 1) * (Bn * Hn);
            uint4 hf0[4], hf1[4];
            #pragma unroll
            for (int j = 0; j < 4; ++j) {
                hf0[j] = *(const uint4*)(hb + hoff0 + j * 32);
                hf1[j] = *(const uint4*)(hb + hoff1 + j * 32);
            }
            #pragma unroll
            for (int j = 0; j < 4; ++j) {
                const int koff = 1024 + wv * 128 + j * 32;
                bf16x8 ahi = *(const bf16x8*)(whi_base + koff);
                bf16x8 alo = *(const bf16x8*)(wlo_base + koff);
                bf16x8 bf0 = as_bf8(hf0[j]);
                bf16x8 bf1 = as_bf8(hf1[j]);
                acc0 = __builtin_amdgcn_mfma_f32_16x16x32_bf16(ahi, bf0, acc0, 0, 0, 0);
                acc0 = __builtin_amdgcn_mfma_f32_16x16x32_bf16(alo, bf0, acc0, 0, 0, 0);
                acc1 = __builtin_amdgcn_mfma_f32_16x16x32_bf16(ahi, bf1, acc1, 0, 0, 0);
                acc1 = __builtin_amdgcn_mfma_f32_16x16x32_bf16(alo, bf1, acc1, 0, 0, 0);
            }
        }

        // ---- cross-wave k-reduction ----
        {
            float* pr0 = lds_r + (wv * 2 + 0) * 256 + l15;
            float* pr1 = lds_r + (wv * 2 + 1) * 256 + l15;
            #pragma unroll
            for (int r = 0; r < 4; ++r) {
                pr0[(qd * 4 + r) * 16] = acc0[r];   // D row = qd*4+r, col = l15
                pr1[(qd * 4 + r) * 16] = acc1[r];
            }
        }
        __syncthreads();
        {
            const int np = tid >> 5, b = tid & 31;
            const int bt = b >> 4, c16 = b & 15;
            float s = 0.f;
            #pragma unroll
            for (int w8 = 0; w8 < 8; ++w8)
                s += lds_r[(w8 * 2 + bt) * 256 + np * 16 + c16];
            lds_g[np * 32 + b] = s;
        }
        __syncthreads();

        // ---- finalize: activations + cell update ----
        if (tid < 128) {
            const int b = tid >> 2, cl = tid & 3;
            float gi = lds_g[(0 * 4 + cl) * 32 + b] + bias0;
            float gf = lds_g[(1 * 4 + cl) * 32 + b] + bias1;
            float gg = lds_g[(2 * 4 + cl) * 32 + b] + bias2;
            float go = lds_g[(3 * 4 + cl) * 32 + b] + bias3;
            float iv = 1.f / (1.f + expf(-gi));
            float fv = 1.f / (1.f + expf(-gf));
            float gv = tanhf(gg);
            float ov = 1.f / (1.f + expf(-go));
            creg = fv * creg + iv * gv;
            float hn = ov * tanhf(creg);
            hbuf[(size_t)(t & 1) * (Bn * Hn) + (size_t)b * Hn + bj * 4 + cl] = f2bf_rne(hn);
            if (t == Tn - 1) out[(size_t)b * Hn + bj * 4 + cl] = hn;
        }
        __syncthreads();                 // waves drain own stores before barrier
        if (tid == 0) {
            __builtin_amdgcn_fence(__ATOMIC_RELEASE, "agent");   // L2 -> LLC
            __hip_atomic_store(&flags[bj], (unsigned)(t + 1),
                               __ATOMIC_RELAXED, __HIP_MEMORY_SCOPE_AGENT);
        }
    }
}

// ---------------------------------------------------------------------------
extern "C" void kernel_launch(void* const* d_in, const int* in_sizes, int n_in,
                              void* d_out, int out_size, void* d_ws, size_t ws_size,
                              hipStream_t stream) {
    const float* x    = (const float*)d_in[0];
    const float* w_ih = (const float*)d_in[1];
    const float* w_hh = (const float*)d_in[2];
    const float* b_ih = (const float*)d_in[3];
    const float* b_hh = (const float*)d_in[4];
    float* out = (float*)d_out;

    char* ws = (char*)d_ws;
    unsigned*       flags = (unsigned*)ws;                      // 1 KB
    unsigned short* hbuf  = (unsigned short*)(ws + 1024);       // 2 x 64 KB bf16
    (void)in_sizes; (void)n_in; (void)out_size; (void)ws_size;

    const size_t smem_bytes = 131584 + 16384 + 2048;            // 150016 B

    lstm_flags_init<<<dim3(1), dim3(256), 0, stream>>>(flags);
    lstm_persist_mfma<<<dim3(256), dim3(512), smem_bytes, stream>>>(
        x, w_ih, w_hh, b_ih, b_hh, hbuf, flags, out);
}

// Round 5
// 4228.830 us; speedup vs baseline: 16.4438x; 1.7420x over previous
//
#include <hip/hip_runtime.h>
#include <cmath>

#define Tn 512
#define Bn 32
#define Hn 1024

typedef short bf16x8 __attribute__((ext_vector_type(8)));
typedef float f32x4 __attribute__((ext_vector_type(4)));

__device__ __forceinline__ unsigned short f2bf_rne(float f) {
    unsigned u = __float_as_uint(f);
    unsigned r = (u + 0x7fffu + ((u >> 16) & 1u)) >> 16;
    return (unsigned short)r;
}
__device__ __forceinline__ float bf2f(unsigned short h) {
    return __uint_as_float((unsigned)h << 16);
}
__device__ __forceinline__ bf16x8 cvt8(float4 a, float4 b) {
    union { unsigned u[4]; bf16x8 v; } o;
    o.u[0] = (unsigned)f2bf_rne(a.x) | ((unsigned)f2bf_rne(a.y) << 16);
    o.u[1] = (unsigned)f2bf_rne(a.z) | ((unsigned)f2bf_rne(a.w) << 16);
    o.u[2] = (unsigned)f2bf_rne(b.x) | ((unsigned)f2bf_rne(b.y) << 16);
    o.u[3] = (unsigned)f2bf_rne(b.z) | ((unsigned)f2bf_rne(b.w) << 16);
    return o.v;
}
__device__ __forceinline__ bf16x8 as_bf8(uint4 u) {
    union { uint4 q; bf16x8 v; } o; o.q = u; return o.v;
}

// ---- explicitly coherent (LLC point-of-coherence) access helpers ----------
// sc0 sc1 = bypass L1+L2 -> no cache-wide buffer_wbl2/buffer_inv fences needed.
// Every asm block self-drains (s_waitcnt vmcnt(0)) so compiler vmcnt
// bookkeeping stays conservative-correct.
__device__ __forceinline__ void gstore_u32_sc(unsigned* p, unsigned v) {
    asm volatile("global_store_dword %0, %1, off sc0 sc1\n\t"
                 "s_waitcnt vmcnt(0)"
                 :: "v"(p), "v"(v) : "memory");
}
__device__ __forceinline__ uint4 gload_u4_sc(const unsigned* p) {
    uint4 r;
    asm volatile("global_load_dwordx4 %0, %1, off sc0 sc1\n\t"
                 "s_waitcnt vmcnt(0)"
                 : "=&v"(r) : "v"(p) : "memory");
    return r;
}
__device__ __forceinline__ void gload_h_sc(const unsigned short* b0,
                                           const unsigned short* b1,
                                           uint4* o0, uint4* o1) {
    asm volatile(
        "global_load_dwordx4 %0, %8, off sc0 sc1\n\t"
        "global_load_dwordx4 %1, %8, off offset:64 sc0 sc1\n\t"
        "global_load_dwordx4 %2, %8, off offset:128 sc0 sc1\n\t"
        "global_load_dwordx4 %3, %8, off offset:192 sc0 sc1\n\t"
        "global_load_dwordx4 %4, %9, off sc0 sc1\n\t"
        "global_load_dwordx4 %5, %9, off offset:64 sc0 sc1\n\t"
        "global_load_dwordx4 %6, %9, off offset:128 sc0 sc1\n\t"
        "global_load_dwordx4 %7, %9, off offset:192 sc0 sc1\n\t"
        "s_waitcnt vmcnt(0)"
        : "=&v"(o0[0]), "=&v"(o0[1]), "=&v"(o0[2]), "=&v"(o0[3]),
          "=&v"(o1[0]), "=&v"(o1[1]), "=&v"(o1[2]), "=&v"(o1[3])
        : "v"(b0), "v"(b1)
        : "memory");
}

// flags zeroed every call (ws is re-poisoned 0xAA before each timed launch)
__global__ void lstm_flags_init(unsigned* flags) { flags[threadIdx.x] = 0u; }

// ---------------------------------------------------------------------------
// Persistent bf16-MFMA LSTM. 256 blocks (1/CU via 146.5 KB LDS) x 512 thr.
// Same verified compute structure as R4; sync path rebuilt:
//   - NO agent fences (no buffer_wbl2 / buffer_inv per step) -> x and W stay
//     L2-resident; only h + flags go through sc0/sc1 coherent ops.
//   - next-step x fragments prefetched into registers before the poll.
// ---------------------------------------------------------------------------
__global__ __launch_bounds__(512, 2) void lstm_persist_mfma(
    const float* __restrict__ x,       // [B,T,H] fp32
    const float* __restrict__ w_ih,    // [4H,H] fp32
    const float* __restrict__ w_hh,    // [4H,H] fp32
    const float* __restrict__ b_ih,    // [4H]
    const float* __restrict__ b_hh,    // [4H]
    unsigned short* __restrict__ hbuf, // ws: 2 x [32][1024] bf16
    unsigned* __restrict__ flags,      // ws: [256] u32, zeroed
    float* __restrict__ out)           // [B,H] fp32
{
    extern __shared__ char smem[];
    unsigned short* lds_w = (unsigned short*)smem;            // 32 x 2056 bf16
    float* lds_r = (float*)(smem + 131584);                   // 16 x 256 f32
    float* lds_g = (float*)(smem + 131584 + 16384);           // 16 x 32 f32

    const int tid = threadIdx.x;
    const int bj  = blockIdx.x;
    const int wv  = tid >> 6;          // 0..7  k-slice
    const int ln  = tid & 63;
    const int l15 = ln & 15;
    const int qd  = ln >> 4;           // 0..3

    // ---- stage W (hi+lo split bf16) into LDS, once ----
    for (int i = 0; i < 16; ++i) {
        int slot = i * 512 + tid;
        int r    = slot >> 9;
        int f4   = slot & 511;
        int n    = (r >> 2) * Hn + bj * 4 + (r & 3);
        float4 v = (f4 < 256) ? ((const float4*)(w_ih + (size_t)n * Hn))[f4]
                              : ((const float4*)(w_hh + (size_t)n * Hn))[f4 - 256];
        unsigned short h0 = f2bf_rne(v.x), h1 = f2bf_rne(v.y);
        unsigned short h2 = f2bf_rne(v.z), h3 = f2bf_rne(v.w);
        unsigned short l0 = f2bf_rne(v.x - bf2f(h0)), l1 = f2bf_rne(v.y - bf2f(h1));
        unsigned short l2 = f2bf_rne(v.z - bf2f(h2)), l3 = f2bf_rne(v.w - bf2f(h3));
        uint2 ph, pl;
        ph.x = (unsigned)h0 | ((unsigned)h1 << 16);
        ph.y = (unsigned)h2 | ((unsigned)h3 << 16);
        pl.x = (unsigned)l0 | ((unsigned)l1 << 16);
        pl.y = (unsigned)l2 | ((unsigned)l3 << 16);
        *(uint2*)(lds_w + (size_t)r        * 2056 + f4 * 4) = ph;
        *(uint2*)(lds_w + (size_t)(r + 16) * 2056 + f4 * 4) = pl;
    }

    float bias0 = 0.f, bias1 = 0.f, bias2 = 0.f, bias3 = 0.f, creg = 0.f;
    if (tid < 128) {
        int col = bj * 4 + (tid & 3);
        bias0 = b_ih[col]          + b_hh[col];
        bias1 = b_ih[Hn + col]     + b_hh[Hn + col];
        bias2 = b_ih[2 * Hn + col] + b_hh[2 * Hn + col];
        bias3 = b_ih[3 * Hn + col] + b_hh[3 * Hn + col];
    }
    __syncthreads();

    const unsigned short* whi_base = lds_w + (size_t)l15 * 2056 + qd * 8;
    const unsigned short* wlo_base = lds_w + (size_t)(l15 + 16) * 2056 + qd * 8;
    const float* xr0 = x + (size_t)l15        * (Tn * Hn) + wv * 128 + qd * 8;
    const float* xr1 = x + (size_t)(16 + l15) * (Tn * Hn) + wv * 128 + qd * 8;
    const size_t hoff0 = (size_t)l15        * Hn + wv * 128 + qd * 8;
    const size_t hoff1 = (size_t)(16 + l15) * Hn + wv * 128 + qd * 8;

    // ---- preload x fragments for t=0 ----
    float4 xa0[4], xb0[4], xa1[4], xb1[4];
    #pragma unroll
    for (int j = 0; j < 4; ++j) {
        xa0[j] = *(const float4*)(xr0 + j * 32);
        xb0[j] = *(const float4*)(xr0 + j * 32 + 4);
        xa1[j] = *(const float4*)(xr1 + j * 32);
        xb1[j] = *(const float4*)(xr1 + j * 32 + 4);
    }

    for (int t = 0; t < Tn; ++t) {
        f32x4 acc0 = {0.f, 0.f, 0.f, 0.f};   // batches  0..15
        f32x4 acc1 = {0.f, 0.f, 0.f, 0.f};   // batches 16..31

        // ---- issue x prefetch for t+1 (in flight across MFMA + poll) ----
        float4 na0[4], nb0[4], na1[4], nb1[4];
        {
            const int tn = (t + 1 < Tn) ? (t + 1) : t;
            const float* p0 = xr0 + (size_t)tn * Hn;
            const float* p1 = xr1 + (size_t)tn * Hn;
            #pragma unroll
            for (int j = 0; j < 4; ++j) {
                na0[j] = *(const float4*)(p0 + j * 32);
                nb0[j] = *(const float4*)(p0 + j * 32 + 4);
                na1[j] = *(const float4*)(p1 + j * 32);
                nb1[j] = *(const float4*)(p1 + j * 32 + 4);
            }
        }

        // ---- x-phase MFMAs (fragments already in registers) ----
        #pragma unroll
        for (int j = 0; j < 4; ++j) {
            const int koff = wv * 128 + j * 32;
            bf16x8 ahi = *(const bf16x8*)(whi_base + koff);
            bf16x8 alo = *(const bf16x8*)(wlo_base + koff);
            bf16x8 bf0 = cvt8(xa0[j], xb0[j]);
            bf16x8 bf1 = cvt8(xa1[j], xb1[j]);
            acc0 = __builtin_amdgcn_mfma_f32_16x16x32_bf16(ahi, bf0, acc0, 0, 0, 0);
            acc0 = __builtin_amdgcn_mfma_f32_16x16x32_bf16(alo, bf0, acc0, 0, 0, 0);
            acc1 = __builtin_amdgcn_mfma_f32_16x16x32_bf16(ahi, bf1, acc1, 0, 0, 0);
            acc1 = __builtin_amdgcn_mfma_f32_16x16x32_bf16(alo, bf1, acc1, 0, 0, 0);
        }

        // ---- grid barrier + h-phase ----
        if (t > 0) {
            if (wv == 0) {
                const unsigned* fp = flags + ln * 4;
                for (;;) {
                    uint4 f = gload_u4_sc(fp);
                    unsigned mn = f.x < f.y ? f.x : f.y;
                    unsigned mo = f.z < f.w ? f.z : f.w;
                    mn = mn < mo ? mn : mo;
                    if (__all((int)(mn >= (unsigned)t))) break;
                }
            }
            __syncthreads();

            const unsigned short* hb = hbuf + (size_t)((t - 1) & 1) * (Bn * Hn);
            uint4 hf0[4], hf1[4];
            gload_h_sc(hb + hoff0, hb + hoff1, hf0, hf1);
            #pragma unroll
            for (int j = 0; j < 4; ++j) {
                const int koff = 1024 + wv * 128 + j * 32;
                bf16x8 ahi = *(const bf16x8*)(whi_base + koff);
                bf16x8 alo = *(const bf16x8*)(wlo_base + koff);
                bf16x8 bf0 = as_bf8(hf0[j]);
                bf16x8 bf1 = as_bf8(hf1[j]);
                acc0 = __builtin_amdgcn_mfma_f32_16x16x32_bf16(ahi, bf0, acc0, 0, 0, 0);
                acc0 = __builtin_amdgcn_mfma_f32_16x16x32_bf16(alo, bf0, acc0, 0, 0, 0);
                acc1 = __builtin_amdgcn_mfma_f32_16x16x32_bf16(ahi, bf1, acc1, 0, 0, 0);
                acc1 = __builtin_amdgcn_mfma_f32_16x16x32_bf16(alo, bf1, acc1, 0, 0, 0);
            }
        }

        // ---- cross-wave k-reduction ----
        {
            float* pr0 = lds_r + (wv * 2 + 0) * 256 + l15;
            float* pr1 = lds_r + (wv * 2 + 1) * 256 + l15;
            #pragma unroll
            for (int r = 0; r < 4; ++r) {
                pr0[(qd * 4 + r) * 16] = acc0[r];   // D row = qd*4+r, col = l15
                pr1[(qd * 4 + r) * 16] = acc1[r];
            }
        }
        __syncthreads();
        {
            const int np = tid >> 5, b = tid & 31;
            const int bt = b >> 4, c16 = b & 15;
            float s = 0.f;
            #pragma unroll
            for (int w8 = 0; w8 < 8; ++w8)
                s += lds_r[(w8 * 2 + bt) * 256 + np * 16 + c16];
            lds_g[np * 32 + b] = s;
        }
        __syncthreads();

        // ---- finalize: activations + cell update; coherent h publish ----
        if (tid < 128) {
            const int b = tid >> 2, cl = tid & 3;
            float gi = lds_g[(0 * 4 + cl) * 32 + b] + bias0;
            float gf = lds_g[(1 * 4 + cl) * 32 + b] + bias1;
            float gg = lds_g[(2 * 4 + cl) * 32 + b] + bias2;
            float go = lds_g[(3 * 4 + cl) * 32 + b] + bias3;
            float iv = 1.f / (1.f + expf(-gi));
            float fv = 1.f / (1.f + expf(-gf));
            float gv = tanhf(gg);
            float ov = 1.f / (1.f + expf(-go));
            creg = fv * creg + iv * gv;
            float hn = ov * tanhf(creg);
            unsigned short hv = f2bf_rne(hn);
            unsigned up = (unsigned)__shfl_xor((int)(unsigned)hv, 1, 64);
            if (!(tid & 1)) {          // cl even: pack [cl, cl+1] into u32
                unsigned pack = (unsigned)hv | (up << 16);
                unsigned short* hw = hbuf + (size_t)(t & 1) * (Bn * Hn)
                                   + (size_t)b * Hn + bj * 4 + cl;
                gstore_u32_sc((unsigned*)hw, pack);   // self-drains vmcnt
            }
            if (t == Tn - 1) out[(size_t)b * Hn + bj * 4 + cl] = hn;
        }
        __syncthreads();               // all h stores acked before flag
        if (tid == 0)
            gstore_u32_sc(&flags[bj], (unsigned)(t + 1));

        // ---- rotate x prefetch regs ----
        #pragma unroll
        for (int j = 0; j < 4; ++j) {
            xa0[j] = na0[j]; xb0[j] = nb0[j];
            xa1[j] = na1[j]; xb1[j] = nb1[j];
        }
    }
}

// ---------------------------------------------------------------------------
extern "C" void kernel_launch(void* const* d_in, const int* in_sizes, int n_in,
                              void* d_out, int out_size, void* d_ws, size_t ws_size,
                              hipStream_t stream) {
    const float* x    = (const float*)d_in[0];
    const float* w_ih = (const float*)d_in[1];
    const float* w_hh = (const float*)d_in[2];
    const float* b_ih = (const float*)d_in[3];
    const float* b_hh = (const float*)d_in[4];
    float* out = (float*)d_out;

    char* ws = (char*)d_ws;
    unsigned*       flags = (unsigned*)ws;                      // 1 KB
    unsigned short* hbuf  = (unsigned short*)(ws + 1024);       // 2 x 64 KB bf16
    (void)in_sizes; (void)n_in; (void)out_size; (void)ws_size;

    const size_t smem_bytes = 131584 + 16384 + 2048;            // 150016 B

    lstm_flags_init<<<dim3(1), dim3(256), 0, stream>>>(flags);
    lstm_persist_mfma<<<dim3(256), dim3(512), smem_bytes, stream>>>(
        x, w_ih, w_hh, b_ih, b_hh, hbuf, flags, out);
}